// Round 11
// baseline (160.836 us; speedup 1.0000x reference)
//
#include <hip/hip_runtime.h>
#include <hip/hip_bf16.h>
#include <cstdint>

typedef float f32x4 __attribute__((ext_vector_type(4)));
typedef __bf16 bf16x8 __attribute__((ext_vector_type(8)));
typedef __bf16 bf16x4 __attribute__((ext_vector_type(4)));
typedef __bf16 bf16x2 __attribute__((ext_vector_type(2)));
typedef short short4v __attribute__((ext_vector_type(4)));
typedef uint32_t uint2v __attribute__((ext_vector_type(2)));

#define MFMA_K32(A, B, C) __builtin_amdgcn_mfma_f32_16x16x32_bf16((A), (B), (C), 0, 0, 0)

// 16x16x16 bf16 MFMA: device resolves one of the first two branches (verified R4/R6);
// the final #else only satisfies the HOST semantic pass and never runs.
#if __has_builtin(__builtin_amdgcn_mfma_f32_16x16x16bf16_1k)
#define MFMA_K16(A, B, C) __builtin_amdgcn_mfma_f32_16x16x16bf16_1k((A), (B), (C), 0, 0, 0)
#elif __has_builtin(__builtin_amdgcn_mfma_f32_16x16x16_bf16)
static __device__ __forceinline__ f32x4 mfma_k16_alt(short4v a, short4v b, f32x4 c) {
    return __builtin_amdgcn_mfma_f32_16x16x16_bf16(*(bf16x4*)&a, *(bf16x4*)&b, c, 0, 0, 0);
}
#define MFMA_K16(A, B, C) mfma_k16_alt((A), (B), (C))
#else
#define MFMA_K16(A, B, C) (C)  // host-pass placeholder only
#endif

#if __has_builtin(__builtin_amdgcn_exp2f)
#define EXP2(x) __builtin_amdgcn_exp2f(x)
#else
#define EXP2(x) exp2f(x)
#endif

// round-to-nearest-even f32 -> bf16 bits
static __device__ __forceinline__ uint16_t f2b(float f) {
    uint32_t u = __float_as_uint(f);
    uint32_t r = (u + 0x7fffu + ((u >> 16) & 1u)) >> 16;
    return (uint16_t)r;
}

// pack two f32 -> bf16x2 dword (low = a, high = b), RNE
static __device__ __forceinline__ uint32_t packbf(float a, float b) {
#if __has_builtin(__builtin_amdgcn_cvt_pk_bf16_f32)
    bf16x2 v = __builtin_amdgcn_cvt_pk_bf16_f32(a, b);
    return *(uint32_t*)&v;
#else
    uint32_t ua = __float_as_uint(a);
    ua += 0x7fffu + ((ua >> 16) & 1u);
    uint32_t ub = __float_as_uint(b);
    ub += 0x7fffu + ((ub >> 16) & 1u);
    return __builtin_amdgcn_perm(ub, ua, 0x07060302);
#endif
}

// ---------------- kernel 1: fused PE + QKV projection --------------------
// grid (128 mtiles of 64 tok, 4 otiles), 256 thr = 4 waves.
// Phase 1: build A-tile (x + PE2D, transposed) in LDS; Phase 2: A-frags to
// regs; Phase 3: reuse the same LDS for W f32->bf16 staging, MFMA, epilogue.
// NOTE: LDS row strides must be multiples of 8 elems (16 B) for b128/b64 DS.
__global__ __launch_bounds__(256) void qkv_fused(const float* __restrict__ x,
                                                 const float* __restrict__ wqf,
                                                 const float* __restrict__ wkf,
                                                 const float* __restrict__ wvf,
                                                 const float* __restrict__ bq,
                                                 const float* __restrict__ bk,
                                                 const float* __restrict__ bv,
                                                 uint16_t* __restrict__ qo,
                                                 uint16_t* __restrict__ ko,
                                                 uint16_t* __restrict__ vo) {
    __shared__ __align__(16) char ubuf[33792];       // AT/WS: [64][264] u16
    __shared__ __align__(16) uint16_t VS[64][72];    // epilogue transpose buffer
    uint16_t (*AT)[264] = (uint16_t(*)[264])ubuf;
    uint16_t (*WS)[264] = (uint16_t(*)[264])ubuf;
    int tid = threadIdx.x, wvi = tid >> 6, lane = tid & 63;
    int c16 = lane & 15, quad = lane >> 4;
    int Mblk = blockIdx.x * 64;
    int O0 = blockIdx.y * 64;
    int bb = Mblk >> 12, nloc = Mblk & 4095;
    // phase 1: tok tile [64 tok][256 c] = x + PE, built transposed
    int nl = tid & 63, cq = tid >> 6;
    int tokloc = nloc + nl;
    float posw = (float)(tokloc & 63), posh = (float)((tokloc >> 6) & 63);
#pragma unroll
    for (int j = 0; j < 16; ++j) {
        int cc = cq * 64 + j * 4;
        float v[4];
#pragma unroll
        for (int e = 0; e < 4; ++e) {
            int c = cc + e;
            int i = (c & 127) >> 1;
            float dt = __expf((float)(2 * i) * -0.07195578415606394f);  // -(ln 1e4)/128
            float sv, cvv;
            __sincosf(((c & 128) ? posh : posw) * dt, &sv, &cvv);
            v[e] = x[((size_t)(bb * 256 + c) << 12) + tokloc] + ((c & 1) ? cvv : sv);
        }
        uint2v pk;
        pk[0] = packbf(v[0], v[1]);
        pk[1] = packbf(v[2], v[3]);
        *(uint2v*)(&AT[nl][cc]) = pk;
    }
    __syncthreads();
    // phase 2: A-frags from LDS (scattered-global loads eliminated)
    bf16x8 af[8];
#pragma unroll
    for (int kk = 0; kk < 8; ++kk)
        af[kk] = *(const bf16x8*)(&AT[wvi * 16 + c16][kk * 32 + quad * 8]);
    f32x4 zero = {0.f, 0.f, 0.f, 0.f};
    int rt = tid >> 2, seg = tid & 3;
    for (int mat = 0; mat < 3; ++mat) {
        const float* Wg = ((mat == 0) ? wqf : (mat == 1) ? wkf : wvf) + (size_t)O0 * 256;
        __syncthreads();  // af read / prior WS+VS readers done
#pragma unroll
        for (int p = 0; p < 16; ++p) {
            int idx = p * 1024 + tid * 4;
            f32x4 w4 = *(const f32x4*)(Wg + idx);
            uint2v pk;
            pk[0] = packbf(w4[0], w4[1]);
            pk[1] = packbf(w4[2], w4[3]);
            *(uint2v*)(&WS[idx >> 8][idx & 255]) = pk;
        }
        __syncthreads();
        f32x4 acc[4] = {zero, zero, zero, zero};
#pragma unroll
        for (int kk = 0; kk < 8; ++kk) {
            int k0 = kk * 32 + quad * 8;
#pragma unroll
            for (int nb = 0; nb < 4; ++nb)
                acc[nb] = MFMA_K32(*(const bf16x8*)(&WS[nb * 16 + c16][k0]),
                                   af[kk], acc[nb]);  // D[o][n]
        }
        if (mat < 2) {
            const float* bias = (mat == 0) ? bq : bk;
            // q gets 1/sqrt(32)*log2(e) folded in (softmax uses exp2)
            float scale = (mat == 0) ? 0.25505654134660127f : 1.0f;
#pragma unroll
            for (int nb = 0; nb < 4; ++nb) {
                int o = O0 + nb * 16 + quad * 4;
                f32x4 bi = *(const f32x4*)(bias + o);
                uint2v pk;
                pk[0] = packbf((acc[nb][0] + bi[0]) * scale, (acc[nb][1] + bi[1]) * scale);
                pk[1] = packbf((acc[nb][2] + bi[2]) * scale, (acc[nb][3] + bi[3]) * scale);
                *(uint2v*)(&VS[wvi * 16 + c16][nb * 16 + quad * 4]) = pk;
            }
            __syncthreads();
            uint16_t* dst = (mat == 0) ? qo : ko;
            int o0 = O0 + seg * 16;
            int h = o0 >> 5, d0 = o0 & 31;
            size_t addr = ((size_t)(bb * 8 + h) * 4096 + nloc + rt) * 32 + d0;
            *(bf16x8*)(dst + addr) = *(const bf16x8*)(&VS[rt][seg * 16]);
            *(bf16x8*)(dst + addr + 8) = *(const bf16x8*)(&VS[rt][seg * 16 + 8]);
        } else {
            const float* bias = bv;
#pragma unroll
            for (int nb = 0; nb < 4; ++nb)
#pragma unroll
                for (int r = 0; r < 4; ++r) {
                    int o = O0 + nb * 16 + quad * 4 + r;
                    VS[nb * 16 + quad * 4 + r][wvi * 16 + c16] = f2b(acc[nb][r] + bias[o]);
                }
            __syncthreads();
            int o = O0 + rt;
            size_t addr = ((size_t)(bb * 8 + (o >> 5)) * 32 + (o & 31)) * 4096 + nloc + seg * 16;
            *(bf16x8*)(vo + addr) = *(const bf16x8*)(&VS[rt][seg * 16]);
            *(bf16x8*)(vo + addr + 8) = *(const bf16x8*)(&VS[rt][seg * 16 + 8]);
        }
    }
}

// ---------------- kernel 2: flash attention, 4-way k-split ---------------
// grid (64 qtiles of 64, 16 bh), block 512 = 8 waves = 2 qstrips x 4 kquarters.
// Wave owns 32 q rows, iterates its 1024-k quarter in 32-k tiles (stride 40:
// 16B-aligned rows). K16-PV trick + ones-frag rowsum; partials via dead LDS.
static __device__ __forceinline__ void attn_qblock(const bf16x8 (&kf)[2],
                                                   const short4v (&vf)[2][2],
                                                   bf16x8 qf, f32x4& oA, f32x4& oB,
                                                   f32x4& oS) {
    f32x4 zero = {0.f, 0.f, 0.f, 0.f};
    const short4v ones = {0x3F80, 0x3F80, 0x3F80, 0x3F80};  // bf16 1.0 x4
    f32x4 s[2];
#pragma unroll
    for (int kc = 0; kc < 2; ++kc) s[kc] = MFMA_K32(kf[kc], qf, zero);
#pragma unroll
    for (int kc = 0; kc < 2; ++kc) {
#pragma unroll
        for (int r = 0; r < 4; ++r) s[kc][r] = EXP2(s[kc][r]);
        union { short4v s4; uint32_t u[2]; } pa;
        pa.u[0] = packbf(s[kc][0], s[kc][1]);
        pa.u[1] = packbf(s[kc][2], s[kc][3]);
        oA = MFMA_K16(pa.s4, vf[0][kc], oA);
        oB = MFMA_K16(pa.s4, vf[1][kc], oB);
        oS = MFMA_K16(pa.s4, ones, oS);
    }
}

__global__ __launch_bounds__(512, 6) void flash(const uint16_t* __restrict__ qb,
                                                const uint16_t* __restrict__ kb,
                                                const uint16_t* __restrict__ vtb,
                                                uint16_t* __restrict__ concat) {
    // per quarter: KT[2][32][40] (5120 B) + VT[2][32][40] (5120 B); x4 = 40960 B
    __shared__ __align__(16) char smem[40960];
    int tid = threadIdx.x, wv = tid >> 6, lane = tid & 63;
    int c16 = lane & 15, quad = lane >> 4;
    int qr = tid >> 7, qt = tid & 127;      // k-quarter (== wv>>1), thread-in-quarter
    int qstrip = wv & 1;
    int bh = blockIdx.y;
    int q0 = (blockIdx.x << 6) + qstrip * 32;
    size_t base = (size_t)bh << 12;

    uint16_t* KTq = (uint16_t*)(smem + qr * 10240);  // [2][32][40], buf stride 1280
    uint16_t* VTq = KTq + 2560;

    // staging: each thread one 16B K slice + one 16B V slice of its quarter's tile
    const uint16_t* kgp = kb + (base + qr * 1024 + (qt >> 2)) * 32 + (qt & 3) * 8;
    const uint16_t* vgp = vtb + ((size_t)bh * 32 + (qt >> 2)) * 4096 + qr * 1024 + (qt & 3) * 8;
    uint16_t* kls = KTq + (qt >> 2) * 40 + (qt & 3) * 8;
    uint16_t* vls = VTq + (qt >> 2) * 40 + (qt & 3) * 8;

    bf16x8 qf0 = *(const bf16x8*)(qb + (base + q0 + c16) * 32 + quad * 8);
    bf16x8 qf1 = *(const bf16x8*)(qb + (base + q0 + 16 + c16) * 32 + quad * 8);

    f32x4 zero = {0.f, 0.f, 0.f, 0.f};
    f32x4 o00 = zero, o01 = zero, o10 = zero, o11 = zero;
    f32x4 oS0 = zero, oS1 = zero;

    *(bf16x8*)kls = *(const bf16x8*)kgp;
    *(bf16x8*)vls = *(const bf16x8*)vgp;
    __syncthreads();

    for (int kt = 0; kt < 32; ++kt) {
        int cur = kt & 1;
        int kn = (kt + 1) & 31;  // last iter re-loads tile 0 (in-bounds, unused)
        bf16x8 kr = *(const bf16x8*)(kgp + (size_t)kn * 1024);
        bf16x8 vr = *(const bf16x8*)(vgp + kn * 32);
        const uint16_t* kfp = KTq + cur * 1280 + c16 * 40 + quad * 8;
        const uint16_t* vfp = VTq + cur * 1280 + c16 * 40 + quad * 4;
        bf16x8 kf[2];
        short4v vf[2][2];
        kf[0] = *(const bf16x8*)(kfp);
        kf[1] = *(const bf16x8*)(kfp + 640);       // k-rows 16..31
        vf[0][0] = *(const short4v*)(vfp);
        vf[0][1] = *(const short4v*)(vfp + 16);    // k 16..31
        vf[1][0] = *(const short4v*)(vfp + 640);   // d 16..31
        vf[1][1] = *(const short4v*)(vfp + 656);
        attn_qblock(kf, vf, qf0, o00, o01, oS0);
        attn_qblock(kf, vf, qf1, o10, o11, oS1);
        *(bf16x8*)(kls + (cur ^ 1) * 1280) = kr;
        *(bf16x8*)(vls + (cur ^ 1) * 1280) = vr;
        __syncthreads();
    }

    // combine 4 k-quarter partials via dead staging LDS: ov[w][comp][lane] f32
    // writers waves 2..7 -> slots 0..5; readers waves 0,1 sum slots {wv,wv+2,wv+4}
    float* ov = (float*)smem;  // [6][24][64] f32 = 36864 B <= 40960, conflict-free
    if (wv >= 2) {
        float* d = ov + (size_t)(wv - 2) * 24 * 64 + lane;
#pragma unroll
        for (int r = 0; r < 4; ++r) {
            d[(0 * 4 + r) * 64] = o00[r];
            d[(1 * 4 + r) * 64] = o01[r];
            d[(2 * 4 + r) * 64] = o10[r];
            d[(3 * 4 + r) * 64] = o11[r];
            d[(4 * 4 + r) * 64] = oS0[r];
            d[(5 * 4 + r) * 64] = oS1[r];
        }
    }
    __syncthreads();
    if (wv < 2) {
#pragma unroll
        for (int part = 0; part < 3; ++part) {
            const float* s = ov + (size_t)(part * 2 + wv) * 24 * 64 + lane;
#pragma unroll
            for (int r = 0; r < 4; ++r) {
                o00[r] += s[(0 * 4 + r) * 64];
                o01[r] += s[(1 * 4 + r) * 64];
                o10[r] += s[(2 * 4 + r) * 64];
                o11[r] += s[(3 * 4 + r) * 64];
                oS0[r] += s[(4 * 4 + r) * 64];
                oS1[r] += s[(5 * 4 + r) * 64];
            }
        }
        int h = bh & 7, bb = bh >> 3;
#pragma unroll
        for (int r = 0; r < 4; ++r) {
            float i0 = 1.f / oS0[r];
            float i1 = 1.f / oS1[r];
            int n = q0 + quad * 4 + r;
            size_t row0 = ((size_t)bb * 4096 + n) * 256 + h * 32;
            size_t row1 = ((size_t)bb * 4096 + n + 16) * 256 + h * 32;
            concat[row0 + c16]      = f2b(o00[r] * i0);
            concat[row0 + 16 + c16] = f2b(o01[r] * i0);
            concat[row1 + c16]      = f2b(o10[r] * i1);
            concat[row1 + 16 + c16] = f2b(o11[r] * i1);
        }
    }
}

// ---------------- kernel 3: output projection, A-tile LDS-staged ---------
__global__ __launch_bounds__(256) void proj_fused(const uint16_t* __restrict__ concat,
                                                  const float* __restrict__ wof,
                                                  const float* __restrict__ bo,
                                                  float* __restrict__ out) {
    __shared__ __align__(16) char ubuf[33792];       // AT/WS: [64][264] u16
    uint16_t (*AT)[264] = (uint16_t(*)[264])ubuf;
    uint16_t (*WS)[264] = (uint16_t(*)[264])ubuf;
    int tid = threadIdx.x, wvi = tid >> 6, lane = tid & 63;
    int c16 = lane & 15, quad = lane >> 4;
    int Mblk = blockIdx.x * 64;
    int O0 = blockIdx.y * 64;
    // phase 1: stage concat tile coalesced
#pragma unroll
    for (int p = 0; p < 8; ++p) {
        int idx = p * 2048 + tid * 8;
        *(bf16x8*)(&AT[idx >> 8][idx & 255]) =
            *(const bf16x8*)(concat + (size_t)Mblk * 256 + idx);
    }
    __syncthreads();
    bf16x8 af[8];
#pragma unroll
    for (int kk = 0; kk < 8; ++kk)
        af[kk] = *(const bf16x8*)(&AT[wvi * 16 + c16][kk * 32 + quad * 8]);
    __syncthreads();
    // phase 2: stage W from f32 into the same LDS
    const float* Wg = wof + (size_t)O0 * 256;
#pragma unroll
    for (int p = 0; p < 16; ++p) {
        int idx = p * 1024 + tid * 4;
        f32x4 w4 = *(const f32x4*)(Wg + idx);
        uint2v pk;
        pk[0] = packbf(w4[0], w4[1]);
        pk[1] = packbf(w4[2], w4[3]);
        *(uint2v*)(&WS[idx >> 8][idx & 255]) = pk;
    }
    __syncthreads();
    f32x4 zero = {0.f, 0.f, 0.f, 0.f};
    f32x4 acc[4] = {zero, zero, zero, zero};
#pragma unroll
    for (int kk = 0; kk < 8; ++kk) {
        int k0 = kk * 32 + quad * 8;
#pragma unroll
        for (int nb = 0; nb < 4; ++nb)
            acc[nb] = MFMA_K32(*(const bf16x8*)(&WS[nb * 16 + c16][k0]),
                               af[kk], acc[nb]);  // D[o][token]
    }
    // R9/R10 BUG was here: n must include the wave's 16-token slice (wvi*16) —
    // af came from AT[wvi*16 + c16]; dropping it made all 4 waves write the
    // same 16 tokens and left 3/4 of the output unwritten.
    int bb = Mblk >> 12, n = (Mblk + wvi * 16 + c16) & 4095;
#pragma unroll
    for (int nb = 0; nb < 4; ++nb)
#pragma unroll
        for (int r = 0; r < 4; ++r) {
            int o = O0 + nb * 16 + quad * 4 + r;
            out[((size_t)(bb * 256 + o) << 12) + n] = acc[nb][r] + bo[o];
        }
}

extern "C" void kernel_launch(void* const* d_in, const int* in_sizes, int n_in,
                              void* d_out, int out_size, void* d_ws, size_t ws_size,
                              hipStream_t stream) {
    const float* x  = (const float*)d_in[0];
    const float* Wq = (const float*)d_in[1];
    const float* bq = (const float*)d_in[2];
    const float* Wk = (const float*)d_in[3];
    const float* bk = (const float*)d_in[4];
    const float* Wv = (const float*)d_in[5];
    const float* bv = (const float*)d_in[6];
    const float* Wo = (const float*)d_in[7];
    const float* bo = (const float*)d_in[8];
    float* out = (float*)d_out;

    uint16_t* ws   = (uint16_t*)d_ws;
    uint16_t* q    = ws;                  // [bh,n,d]
    uint16_t* k    = q + 2097152;         // [bh,n,d]
    uint16_t* vt   = k + 2097152;         // [bh,d,n]
    uint16_t* cc   = vt + 2097152;        // [b,n,c]

    qkv_fused<<<dim3(128, 4), 256, 0, stream>>>(x, Wq, Wk, Wv, bq, bk, bv, q, k, vt);
    flash<<<dim3(64, 16), 512, 0, stream>>>(q, k, vt, cc);
    proj_fused<<<dim3(128, 4), 256, 0, stream>>>(cc, Wo, bo, out);
}

// Round 12
// 152.462 us; speedup vs baseline: 1.0549x; 1.0549x over previous
//
#include <hip/hip_runtime.h>
#include <hip/hip_bf16.h>
#include <cstdint>

typedef float f32x4 __attribute__((ext_vector_type(4)));
typedef __bf16 bf16x8 __attribute__((ext_vector_type(8)));
typedef __bf16 bf16x4 __attribute__((ext_vector_type(4)));
typedef __bf16 bf16x2 __attribute__((ext_vector_type(2)));
typedef short short4v __attribute__((ext_vector_type(4)));
typedef uint32_t uint2v __attribute__((ext_vector_type(2)));

#define MFMA_K32(A, B, C) __builtin_amdgcn_mfma_f32_16x16x32_bf16((A), (B), (C), 0, 0, 0)

// 16x16x16 bf16 MFMA: device resolves one of the first two branches (verified R4/R6);
// the final #else only satisfies the HOST semantic pass and never runs.
#if __has_builtin(__builtin_amdgcn_mfma_f32_16x16x16bf16_1k)
#define MFMA_K16(A, B, C) __builtin_amdgcn_mfma_f32_16x16x16bf16_1k((A), (B), (C), 0, 0, 0)
#elif __has_builtin(__builtin_amdgcn_mfma_f32_16x16x16_bf16)
static __device__ __forceinline__ f32x4 mfma_k16_alt(short4v a, short4v b, f32x4 c) {
    return __builtin_amdgcn_mfma_f32_16x16x16_bf16(*(bf16x4*)&a, *(bf16x4*)&b, c, 0, 0, 0);
}
#define MFMA_K16(A, B, C) mfma_k16_alt((A), (B), (C))
#else
#define MFMA_K16(A, B, C) (C)  // host-pass placeholder only
#endif

#if __has_builtin(__builtin_amdgcn_exp2f)
#define EXP2(x) __builtin_amdgcn_exp2f(x)
#else
#define EXP2(x) exp2f(x)
#endif

// round-to-nearest-even f32 -> bf16 bits
static __device__ __forceinline__ uint16_t f2b(float f) {
    uint32_t u = __float_as_uint(f);
    uint32_t r = (u + 0x7fffu + ((u >> 16) & 1u)) >> 16;
    return (uint16_t)r;
}

// pack two f32 -> bf16x2 dword (low = a, high = b), RNE
static __device__ __forceinline__ uint32_t packbf(float a, float b) {
#if __has_builtin(__builtin_amdgcn_cvt_pk_bf16_f32)
    bf16x2 v = __builtin_amdgcn_cvt_pk_bf16_f32(a, b);
    return *(uint32_t*)&v;
#else
    uint32_t ua = __float_as_uint(a);
    ua += 0x7fffu + ((ua >> 16) & 1u);
    uint32_t ub = __float_as_uint(b);
    ub += 0x7fffu + ((ub >> 16) & 1u);
    return __builtin_amdgcn_perm(ub, ua, 0x07060302);
#endif
}

// ---------------- kernel 0: merged W f32->bf16 convert + peadd -----------
// blocks 0..1023: wconv; blocks 1024..1535: tok = (x+PE) transposed (R8 body)
__global__ __launch_bounds__(256) void prep(const float* __restrict__ wq,
                                            const float* __restrict__ wk,
                                            const float* __restrict__ wv,
                                            const float* __restrict__ wo,
                                            const float* __restrict__ x,
                                            uint16_t* __restrict__ Wb,
                                            uint16_t* __restrict__ tok) {
    int bid = blockIdx.x, t = threadIdx.x;
    if (bid < 1024) {
        int idx = bid * 256 + t;
        int which = idx >> 16, off = idx & 65535;
        const float* s = (which == 0) ? wq : (which == 1) ? wk : (which == 2) ? wv : wo;
        Wb[idx] = f2b(s[off]);
        return;
    }
    __shared__ uint16_t T[64][65];
    int pb = bid - 1024;
    int nt = pb & 63, ct = (pb >> 6) & 3, bb = pb >> 8;
    int n0 = nt << 6, c0 = ct << 6;
    int nl = t & 63, cq = t >> 6;
    int n = n0 + nl;
    float posh = (float)nt;
    float posw = (float)nl;
#pragma unroll
    for (int p = 0; p < 16; ++p) {
        int cl = cq * 16 + p;
        int cc = c0 + cl;
        int i = (cc & 127) >> 1;
        float dt = __expf((float)(2 * i) * -0.07195578415606394f);  // -(ln 1e4)/128
        float sv, cv;
        __sincosf(((cc & 128) ? posh : posw) * dt, &sv, &cv);
        float pe = (cc & 1) ? cv : sv;
        T[cl][nl] = f2b(x[((size_t)(bb * 256 + cc) << 12) + n] + pe);
    }
    __syncthreads();
#pragma unroll
    for (int p = 0; p < 16; ++p) {
        int tl = cq * 16 + p;
        tok[(((size_t)(bb << 12) | (n0 + tl)) << 8) + c0 + nl] = T[nl][tl];
    }
}

// ---------------- kernel 1: QKV projection -------------------------------
// grid (128 mtiles, 4 otiles), 256 thr = 4 waves. A-tile LDS-staged
// (coalesced, replaces R7's lane-stride-512B scattered b128 A loads);
// q/k direct packed stores (R7); V via VS transpose (R8) -> coalesced.
__global__ __launch_bounds__(256) void qkv_gemm(const uint16_t* __restrict__ tok,
                                                const uint16_t* __restrict__ Wall,
                                                const float* __restrict__ bq,
                                                const float* __restrict__ bk,
                                                const float* __restrict__ bv,
                                                uint16_t* __restrict__ qo,
                                                uint16_t* __restrict__ ko,
                                                uint16_t* __restrict__ vo) {
    __shared__ __align__(16) char ubuf[33792];       // AT/WS: [64][264] u16
    __shared__ __align__(16) uint16_t VS[64][72];
    uint16_t (*AT)[264] = (uint16_t(*)[264])ubuf;
    uint16_t (*WS)[264] = (uint16_t(*)[264])ubuf;
    int tid = threadIdx.x, wvi = tid >> 6, lane = tid & 63;
    int c16 = lane & 15, quad = lane >> 4;
    int Mblk = blockIdx.x * 64;
    int M0 = Mblk + wvi * 16;
    int O0 = blockIdx.y * 64;
    int bb = M0 >> 12, n = (M0 + c16) & 4095;
    int nloc = Mblk & 4095;
    // stage A-tile coalesced: 64 tokens x 256 ch
#pragma unroll
    for (int p = 0; p < 8; ++p) {
        int idx = p * 2048 + tid * 8;
        *(bf16x8*)(&AT[idx >> 8][idx & 255]) =
            *(const bf16x8*)(tok + (size_t)Mblk * 256 + idx);
    }
    __syncthreads();
    bf16x8 af[8];
#pragma unroll
    for (int kk = 0; kk < 8; ++kk)
        af[kk] = *(const bf16x8*)(&AT[wvi * 16 + c16][kk * 32 + quad * 8]);
    f32x4 zero = {0.f, 0.f, 0.f, 0.f};
    int rt = tid >> 2, seg = tid & 3;
    for (int mat = 0; mat < 3; ++mat) {
        const uint16_t* Wg = Wall + (size_t)mat * 65536 + (size_t)O0 * 256;
        __syncthreads();  // af loaded / prior WS readers done
#pragma unroll
        for (int p = 0; p < 8; ++p) {
            int idx = p * 2048 + tid * 8;
            *(bf16x8*)(&WS[idx >> 8][idx & 255]) = *(const bf16x8*)(Wg + idx);
        }
        __syncthreads();
        f32x4 acc[4] = {zero, zero, zero, zero};
#pragma unroll
        for (int kk = 0; kk < 8; ++kk) {
            int k0 = kk * 32 + quad * 8;
#pragma unroll
            for (int nb = 0; nb < 4; ++nb)
                acc[nb] = MFMA_K32(*(const bf16x8*)(&WS[nb * 16 + c16][k0]),
                                   af[kk], acc[nb]);  // D[o][n]
        }
        if (mat < 2) {
            const float* bias = (mat == 0) ? bq : bk;
            // q gets 1/sqrt(32)*log2(e) folded in (softmax uses exp2)
            float scale = (mat == 0) ? 0.25505654134660127f : 1.0f;
            uint16_t* dst = (mat == 0) ? qo : ko;
#pragma unroll
            for (int nb = 0; nb < 4; ++nb) {
                int o = O0 + nb * 16 + quad * 4;          // o..o+3, same head
                f32x4 bi = *(const f32x4*)(bias + o);
                int h = o >> 5, dd = o & 31;
                uint2v pk;
                pk[0] = packbf((acc[nb][0] + bi[0]) * scale, (acc[nb][1] + bi[1]) * scale);
                pk[1] = packbf((acc[nb][2] + bi[2]) * scale, (acc[nb][3] + bi[3]) * scale);
                *(uint2v*)(dst + ((size_t)(bb * 8 + h) * 4096 + n) * 32 + dd) = pk;
            }
        } else {
            // V^T via VS transpose -> coalesced 16B stores
#pragma unroll
            for (int nb = 0; nb < 4; ++nb)
#pragma unroll
                for (int r = 0; r < 4; ++r) {
                    int o = O0 + nb * 16 + quad * 4 + r;
                    VS[nb * 16 + quad * 4 + r][wvi * 16 + c16] = f2b(acc[nb][r] + bv[o]);
                }
            __syncthreads();
            int o = O0 + rt;
            size_t addr = ((size_t)(bb * 8 + (o >> 5)) * 32 + (o & 31)) * 4096 + nloc + seg * 16;
            *(bf16x8*)(vo + addr) = *(const bf16x8*)(&VS[rt][seg * 16]);
            *(bf16x8*)(vo + addr + 8) = *(const bf16x8*)(&VS[rt][seg * 16 + 8]);
        }
    }
}

// ---------------- kernel 2: flash attention (R7 + manual 2x unroll) ------
// grid (32 qtiles of 128, 16 bh), block 512 = 8 waves; wave owns 32 q rows,
// k-half of 2048 in 64-k tiles. K16-PV trick + ones-frag rowsum.
static __device__ __forceinline__ void attn_qblock(const bf16x8 (&kf)[4],
                                                   const short4v (&vf)[2][4],
                                                   bf16x8 qf, f32x4& oA, f32x4& oB,
                                                   f32x4& oS) {
    f32x4 zero = {0.f, 0.f, 0.f, 0.f};
    const short4v ones = {0x3F80, 0x3F80, 0x3F80, 0x3F80};  // bf16 1.0 x4
    f32x4 s[4];
#pragma unroll
    for (int kc = 0; kc < 4; ++kc) s[kc] = MFMA_K32(kf[kc], qf, zero);
#pragma unroll
    for (int kc = 0; kc < 4; ++kc) {
#pragma unroll
        for (int r = 0; r < 4; ++r) s[kc][r] = EXP2(s[kc][r]);
        union { short4v s4; uint32_t u[2]; } pa;
        pa.u[0] = packbf(s[kc][0], s[kc][1]);
        pa.u[1] = packbf(s[kc][2], s[kc][3]);
        oA = MFMA_K16(pa.s4, vf[0][kc], oA);
        oB = MFMA_K16(pa.s4, vf[1][kc], oB);
        oS = MFMA_K16(pa.s4, ones, oS);
    }
}

__global__ __launch_bounds__(512, 4) void flash(const uint16_t* __restrict__ qb,
                                                const uint16_t* __restrict__ kb,
                                                const uint16_t* __restrict__ vtb,
                                                uint16_t* __restrict__ concat) {
    // per half: Kt[2][64][40] (10240 B) + Vt[2][32][72] (9216 B) = 19456 B
    __shared__ __align__(16) char smem[38912];
    int tid = threadIdx.x, wv = tid >> 6, lane = tid & 63;
    int c16 = lane & 15, quad = lane >> 4;
    int half = tid >> 8, t2 = tid & 255;
    int bh = blockIdx.y;
    int q0 = (blockIdx.x << 7) + (wv & 3) * 32;
    size_t base = (size_t)bh << 12;

    uint16_t* KT = (uint16_t*)(smem + half * 19456);          // [2][64][40]
    uint16_t* VT = (uint16_t*)(smem + half * 19456 + 10240);  // [2][32][72]

    const uint16_t* kgp = kb + (base + (size_t)half * 2048 + (t2 >> 2)) * 32 + (t2 & 3) * 8;
    const uint16_t* vgp = vtb + ((size_t)bh * 32 + (t2 >> 3)) * 4096 + half * 2048 + (t2 & 7) * 8;
    uint16_t* kls = KT + (t2 >> 2) * 40 + (t2 & 3) * 8;   // + buf*2560
    uint16_t* vls = VT + (t2 >> 3) * 72 + (t2 & 7) * 8;   // + buf*2304

    bf16x8 qf0 = *(const bf16x8*)(qb + (base + q0 + c16) * 32 + quad * 8);
    bf16x8 qf1 = *(const bf16x8*)(qb + (base + q0 + 16 + c16) * 32 + quad * 8);

    f32x4 zero = {0.f, 0.f, 0.f, 0.f};
    f32x4 o00 = zero, o01 = zero, o10 = zero, o11 = zero;
    f32x4 oS0 = zero, oS1 = zero;

    *(bf16x8*)kls = *(const bf16x8*)kgp;
    *(bf16x8*)vls = *(const bf16x8*)vgp;
    __syncthreads();

    // manual 2x unroll: CUR is a literal -> constant LDS offsets, no dynamic
    // cur/kn address VALU in the hot loop
#define FSTEP(CUR, KN)                                                        \
    {                                                                         \
        bf16x8 kr = *(const bf16x8*)(kgp + (size_t)(KN) * 2048);              \
        bf16x8 vr = *(const bf16x8*)(vgp + (KN) * 64);                        \
        const uint16_t* kfp = KT + (CUR) * 2560 + c16 * 40 + quad * 8;        \
        const uint16_t* vfp = VT + (CUR) * 2304 + c16 * 72 + quad * 4;        \
        bf16x8 kf[4];                                                         \
        short4v vf[2][4];                                                     \
        _Pragma("unroll") for (int kc = 0; kc < 4; ++kc)                      \
            kf[kc] = *(const bf16x8*)(kfp + kc * 640);                        \
        _Pragma("unroll") for (int kc = 0; kc < 4; ++kc) {                    \
            vf[0][kc] = *(const short4v*)(vfp + kc * 16);                     \
            vf[1][kc] = *(const short4v*)(vfp + 1152 + kc * 16);              \
        }                                                                     \
        attn_qblock(kf, vf, qf0, o00, o01, oS0);                              \
        attn_qblock(kf, vf, qf1, o10, o11, oS1);                              \
        *(bf16x8*)(kls + (1 - (CUR)) * 2560) = kr;                            \
        *(bf16x8*)(vls + (1 - (CUR)) * 2304) = vr;                            \
        __syncthreads();                                                      \
    }
    for (int i2 = 0; i2 < 16; ++i2) {
        FSTEP(0, 2 * i2 + 1)
        FSTEP(1, (2 * i2 + 2) & 31)   // last iter re-stages tile 0 (unused)
    }
#undef FSTEP

    float* ov = (float*)smem;  // [4][64][25] = 25600 B
    if (wv >= 4) {
        float* d = ov + ((wv - 4) * 64 + lane) * 25;
#pragma unroll
        for (int r = 0; r < 4; ++r) {
            d[r] = o00[r]; d[4 + r] = o01[r]; d[8 + r] = o10[r]; d[12 + r] = o11[r];
            d[16 + r] = oS0[r]; d[20 + r] = oS1[r];
        }
    }
    __syncthreads();
    if (wv < 4) {
        const float* s = ov + (wv * 64 + lane) * 25;
#pragma unroll
        for (int r = 0; r < 4; ++r) {
            o00[r] += s[r]; o01[r] += s[4 + r]; o10[r] += s[8 + r]; o11[r] += s[12 + r];
            oS0[r] += s[16 + r]; oS1[r] += s[20 + r];
        }
        int h = bh & 7, bb = bh >> 3;
#pragma unroll
        for (int r = 0; r < 4; ++r) {
            float i0 = 1.f / oS0[r];
            float i1 = 1.f / oS1[r];
            int n = q0 + quad * 4 + r;
            size_t row0 = ((size_t)bb * 4096 + n) * 256 + h * 32;
            size_t row1 = ((size_t)bb * 4096 + n + 16) * 256 + h * 32;
            concat[row0 + c16]      = f2b(o00[r] * i0);
            concat[row0 + 16 + c16] = f2b(o01[r] * i0);
            concat[row1 + c16]      = f2b(o10[r] * i1);
            concat[row1 + 16 + c16] = f2b(o11[r] * i1);
        }
    }
}

// ---------------- kernel 3: output projection, A-tile + W LDS-staged -----
__global__ __launch_bounds__(256) void proj_gemm(const uint16_t* __restrict__ concat,
                                                 const uint16_t* __restrict__ Wob,
                                                 const float* __restrict__ bo,
                                                 float* __restrict__ out) {
    __shared__ __align__(16) char ubuf[33792];       // AT/WS: [64][264] u16
    uint16_t (*AT)[264] = (uint16_t(*)[264])ubuf;
    uint16_t (*WS)[264] = (uint16_t(*)[264])ubuf;
    int tid = threadIdx.x, wvi = tid >> 6, lane = tid & 63;
    int c16 = lane & 15, quad = lane >> 4;
    int Mblk = blockIdx.x * 64;
    int O0 = blockIdx.y * 64;
#pragma unroll
    for (int p = 0; p < 8; ++p) {
        int idx = p * 2048 + tid * 8;
        *(bf16x8*)(&AT[idx >> 8][idx & 255]) =
            *(const bf16x8*)(concat + (size_t)Mblk * 256 + idx);
    }
    __syncthreads();
    bf16x8 af[8];
#pragma unroll
    for (int kk = 0; kk < 8; ++kk)
        af[kk] = *(const bf16x8*)(&AT[wvi * 16 + c16][kk * 32 + quad * 8]);
    __syncthreads();
    const uint16_t* Wg = Wob + (size_t)O0 * 256;
#pragma unroll
    for (int p = 0; p < 8; ++p) {
        int idx = p * 2048 + tid * 8;
        *(bf16x8*)(&WS[idx >> 8][idx & 255]) = *(const bf16x8*)(Wg + idx);
    }
    __syncthreads();
    f32x4 zero = {0.f, 0.f, 0.f, 0.f};
    f32x4 acc[4] = {zero, zero, zero, zero};
#pragma unroll
    for (int kk = 0; kk < 8; ++kk) {
        int k0 = kk * 32 + quad * 8;
#pragma unroll
        for (int nb = 0; nb < 4; ++nb)
            acc[nb] = MFMA_K32(*(const bf16x8*)(&WS[nb * 16 + c16][k0]),
                               af[kk], acc[nb]);  // D[o][token]
    }
    // token index must include the wave slice (wvi*16) — R9/R10 lesson
    int bb = Mblk >> 12, n = (Mblk + wvi * 16 + c16) & 4095;
#pragma unroll
    for (int nb = 0; nb < 4; ++nb)
#pragma unroll
        for (int r = 0; r < 4; ++r) {
            int o = O0 + nb * 16 + quad * 4 + r;
            out[((size_t)(bb * 256 + o) << 12) + n] = acc[nb][r] + bo[o];
        }
}

extern "C" void kernel_launch(void* const* d_in, const int* in_sizes, int n_in,
                              void* d_out, int out_size, void* d_ws, size_t ws_size,
                              hipStream_t stream) {
    const float* x  = (const float*)d_in[0];
    const float* Wq = (const float*)d_in[1];
    const float* bq = (const float*)d_in[2];
    const float* Wk = (const float*)d_in[3];
    const float* bk = (const float*)d_in[4];
    const float* Wv = (const float*)d_in[5];
    const float* bv = (const float*)d_in[6];
    const float* Wo = (const float*)d_in[7];
    const float* bo = (const float*)d_in[8];
    float* out = (float*)d_out;

    uint16_t* ws   = (uint16_t*)d_ws;
    uint16_t* Wb   = ws;                  // 4*65536 bf16
    uint16_t* tok  = Wb + 262144;         // [b,N,c]
    uint16_t* q    = tok + 2097152;       // [bh,n,d]
    uint16_t* k    = q + 2097152;         // [bh,n,d]
    uint16_t* vt   = k + 2097152;         // [bh,d,n]
    uint16_t* cc   = vt + 2097152;        // [b,n,c]

    prep<<<1536, 256, 0, stream>>>(Wq, Wk, Wv, Wo, x, Wb, tok);
    qkv_gemm<<<dim3(128, 4), 256, 0, stream>>>(tok, Wb, bq, bk, bv, q, k, vt);
    flash<<<dim3(32, 16), 512, 0, stream>>>(q, k, vt, cc);
    proj_gemm<<<dim3(128, 4), 256, 0, stream>>>(cc, Wb + 3 * 65536, bo, out);
}